// Round 9
// baseline (1825.557 us; speedup 1.0000x reference)
//
#include <hip/hip_runtime.h>
#include <cmath>

#define T_STEPS 300
#define NBATCH  256
#define NNEUR   1024
#define BN      (NBATCH * NNEUR)
#define RING_WORDS (NBATCH * NNEUR)   // one ring slot = 256x1024 u32 = 1 MiB

typedef _Float16 f16x8 __attribute__((ext_vector_type(8)));
typedef float    f32x4 __attribute__((ext_vector_type(4)));
typedef unsigned u32x4 __attribute__((ext_vector_type(4)));

// ---- device-scope primitives (commit at / read from the L3 coherence point) -----------
__device__ __forceinline__ void st_u4_dev(unsigned* p, u32x4 v) {
    asm volatile("global_store_dwordx4 %0, %1, off sc0 sc1" :: "v"(p), "v"(v) : "memory");
}
__device__ __forceinline__ u32x4 ld_u4_dev(const unsigned* p) {
    u32x4 d; asm volatile("global_load_dwordx4 %0, %1, off sc0 sc1" : "=v"(d) : "v"(p)); return d;
}
__device__ __forceinline__ void st_f4_dev(float* p, f32x4 v) {
    asm volatile("global_store_dwordx4 %0, %1, off sc0 sc1" :: "v"(p), "v"(v) : "memory");
}
__device__ __forceinline__ f32x4 ld_f4_dev(const float* p) {
    f32x4 d; asm volatile("global_load_dwordx4 %0, %1, off sc0 sc1" : "=v"(d) : "v"(p)); return d;
}
__device__ __forceinline__ void st_dw_dev(unsigned* p, unsigned v) {
    asm volatile("global_store_dword %0, %1, off sc0 sc1" :: "v"(p), "v"(v) : "memory");
}
__device__ __forceinline__ unsigned ld_dw_dev(const unsigned* p) {
    unsigned v;
    asm volatile("global_load_dword %0, %1, off sc0 sc1\n\ts_waitcnt vmcnt(0)"
                 : "=v"(v) : "v"(p) : "memory");
    return v;
}
__device__ __forceinline__ void drain_vm() {
    asm volatile("s_waitcnt vmcnt(0)" ::: "memory");
}
// branchless tanh: 1 - 2/(e^{2x}+1); ~1e-6 abs error (margin: threshold/absmax = 4.8x)
__device__ __forceinline__ float fast_tanh(float x) {
    float e = __expf(2.0f * x);
    return 1.0f - 2.0f / (e + 1.0f);
}

// ---- shared prologue helpers -----------------------------------------------------------
__device__ __forceinline__ void detect_mask(const void* mask, int lane,
                                            bool& mask_f32, bool& mask_u8) {
    unsigned mb = 0;
    const unsigned* m32 = (const unsigned*)mask;
    for (int idx = lane; idx < 1024; idx += 64) {
        unsigned v = m32[idx];
        if (v == 0x3F800000u) mb |= 2u;
        else if (v > 1u)      mb |= 1u;
    }
    mask_f32 = __ballot(mb & 2u) != 0ull;
    mask_u8  = !mask_f32 && (__ballot(mb & 1u) != 0ull);
}

__device__ __forceinline__ void build_bfr(const float* W, const void* mask,
                                          bool mask_f32, bool mask_u8,
                                          int m, int w, int l15, int lq, f16x8 bfr[4][8]) {
    #pragma unroll
    for (int ns = 0; ns < 4; ++ns) {
        const size_t rowbase = (size_t)(64 * m + 16 * ns + l15) * NNEUR + 256 * w + 8 * lq;
        #pragma unroll
        for (int kk = 0; kk < 8; ++kk) {
            const size_t i0 = rowbase + 32 * kk;
            f16x8 bv;
            #pragma unroll
            for (int j = 0; j < 8; ++j) {
                const size_t i = i0 + j;
                bool mv;
                if (mask_f32)     mv = ((const float*)mask)[i] != 0.0f;
                else if (mask_u8) mv = ((const unsigned char*)mask)[i] != 0;
                else              mv = ((const int*)mask)[i] != 0;
                bv[j] = (_Float16)(mv ? W[i] : 0.0f);
            }
            bfr[ns][kk] = bv;
        }
    }
}

// ================= FAST kernel: tagged ring, optional canary-gated fetch ================
// word = ((t+1)<<16)|f16bits(r_t); slot = (t+1)&1; ring reuse skew<=1 proof as R6/R7.
// CANARY: producer drains its WG's ring stores (vmcnt0 + barrier) then tid0 publishes a
// per-WG step counter; consumer waves spin on ONE dwordx4 of 4 canaries (16B, uniform
// across lanes -> 1 transaction/wave/iter) instead of re-loading the 16KB data tile per
// poll iteration. Data tags are still validated after the single fetch (defense in depth).
template<bool CANARY>
__global__ void __launch_bounds__(256, 1)
rnn_fast(const float* __restrict__ inp, const float* __restrict__ nz,
         const float* __restrict__ W, const float* __restrict__ bias,
         const void* __restrict__ mask, unsigned* ws, float* out) {
    const int bid  = blockIdx.x;
    const int g    = bid & 15;
    const int m    = bid >> 4;
    const int tid  = threadIdx.x;
    const int w    = tid >> 6;
    const int lane = tid & 63;
    const int l15  = lane & 15;
    const int lq   = lane >> 4;

    unsigned* canary = ws;                         // 4KB block (256 used; 16/group, 16B/wave)
    unsigned* ring   = CANARY ? (ws + 1024) : ws;  // 2 MiB of tagged words

    __shared__ __align__(16) float part[2][4][16][68];

    bool mask_f32, mask_u8;
    detect_mask(mask, lane, mask_f32, mask_u8);
    f16x8 bfr[4][8];
    build_bfr(W, mask, mask_f32, mask_u8, m, w, l15, lq, bfr);

    const int orow = tid >> 4;
    const int ocol = (tid & 15) << 2;
    const int grow = 16 * g + orow;
    const int gcol = 64 * m + ocol;
    const float4 b4 = *(const float4*)(bias + gcol);

    float x0 = 0.f, x1 = 0.f, x2 = 0.f, x3 = 0.f;

    // r_0 = tanh(0) = 0: out slice only; t=0 iteration skips the poll entirely.
    *(float4*)(out + (size_t)grow * NNEUR + gcol) = make_float4(0.f, 0.f, 0.f, 0.f);

    const unsigned* rbase = ring + (size_t)(16 * g + l15) * NNEUR + 256 * w + 8 * lq;
    unsigned* const wslot = ring + (size_t)grow * NNEUR + gcol;

    for (int t = 0; t < T_STEPS; ++t) {
        const size_t io = (size_t)t * BN + (size_t)grow * NNEUR + gcol;
        const float4 in4 = *(const float4*)(inp + io);
        const float4 nz4 = *(const float4*)(nz + io);

        f16x8 a[8];
        if (t > 0) {
            const unsigned tgu = (unsigned)(t + 1);
            if (CANARY) {
                // ---- cheap gate: one 16B canary load, same addr all lanes, uniform exit ----
                const unsigned* cp = &canary[(g << 4) + (w << 2)];  // 16B-aligned, waves 4w..4w+3
                int budget = 1 << 13;
                for (;;) {
                    u32x4 cv = ld_u4_dev(cp);
                    drain_vm();
                    unsigned mn = cv[0] < cv[1] ? cv[0] : cv[1];
                    mn = mn < cv[2] ? mn : cv[2];
                    mn = mn < cv[3] ? mn : cv[3];
                    if (mn >= tgu) break;
                    if (--budget <= 0) break;          // failsafe: never hang
                }
                __builtin_amdgcn_sched_barrier(0);
            }
            // ---- data fetch (expected 1 iteration when CANARY) + tag validation ----
            const unsigned tgt = tgu << 16;
            const unsigned* rb = rbase + (size_t)(tgu & 1) * RING_WORDS;
            u32x4 wv[16];
            int budget = CANARY ? (1 << 10) : (1 << 13);
            for (;;) {
                #pragma unroll
                for (int kk = 0; kk < 8; ++kk) {
                    wv[2 * kk]     = ld_u4_dev(rb + 32 * kk);
                    wv[2 * kk + 1] = ld_u4_dev(rb + 32 * kk + 4);
                }
                drain_vm();
                unsigned bad = 0;
                #pragma unroll
                for (int i = 0; i < 16; ++i) {
                    const u32x4 x = wv[i] ^ tgt;      // hi16 == 0 iff fresh
                    bad |= (x[0] | x[1] | x[2] | x[3]) & 0xFFFF0000u;
                }
                if (__ballot(bad != 0u) == 0ull) break;
                if (--budget <= 0) break;             // failsafe: never hang
                __builtin_amdgcn_s_sleep(1);
            }
            #pragma unroll
            for (int kk = 0; kk < 8; ++kk) {
                const u32x4 lo = wv[2 * kk], hi = wv[2 * kk + 1];
                u32x4 p;
                p[0] = (lo[0] & 0xFFFFu) | (lo[1] << 16);
                p[1] = (lo[2] & 0xFFFFu) | (lo[3] << 16);
                p[2] = (hi[0] & 0xFFFFu) | (hi[1] << 16);
                p[3] = (hi[2] & 0xFFFFu) | (hi[3] << 16);
                a[kk] = __builtin_bit_cast(f16x8, p);
            }
        } else {
            #pragma unroll
            for (int kk = 0; kk < 8; ++kk) a[kk] = f16x8{};
        }

        f32x4 acc[4] = {};
        #pragma unroll
        for (int kk = 0; kk < 8; ++kk)
            #pragma unroll
            for (int ns = 0; ns < 4; ++ns)
                acc[ns] = __builtin_amdgcn_mfma_f32_16x16x32_f16(a[kk], bfr[ns][kk], acc[ns], 0, 0, 0);

        const int pb = t & 1;
        #pragma unroll
        for (int ns = 0; ns < 4; ++ns)
            #pragma unroll
            for (int r = 0; r < 4; ++r)
                part[pb][w][(lq << 2) + r][(ns << 4) + l15] = acc[ns][r];

        __syncthreads();

        f32x4 s = *(const f32x4*)&part[pb][0][orow][ocol];
        #pragma unroll
        for (int wv2 = 1; wv2 < 4; ++wv2)
            s += *(const f32x4*)&part[pb][wv2][orow][ocol];

        x0 = 0.9f * x0 + 0.1f * (s[0] + in4.x + b4.x) + 0.003f * nz4.x;
        x1 = 0.9f * x1 + 0.1f * (s[1] + in4.y + b4.y) + 0.003f * nz4.y;
        x2 = 0.9f * x2 + 0.1f * (s[2] + in4.z + b4.z) + 0.003f * nz4.z;
        x3 = 0.9f * x3 + 0.1f * (s[3] + in4.w + b4.w) + 0.003f * nz4.w;

        const float r0 = fast_tanh(x0), r1 = fast_tanh(x1),
                    r2 = fast_tanh(x2), r3 = fast_tanh(x3);

        *(float4*)(out + (size_t)(t + 1) * BN + (size_t)grow * NNEUR + gcol)
            = make_float4(r0, r1, r2, r3);

        {   // tagged publish
            const unsigned tg = (unsigned)(t + 2) << 16;
            u32x4 pv;
            pv[0] = tg | (unsigned)__builtin_bit_cast(unsigned short, (_Float16)r0);
            pv[1] = tg | (unsigned)__builtin_bit_cast(unsigned short, (_Float16)r1);
            pv[2] = tg | (unsigned)__builtin_bit_cast(unsigned short, (_Float16)r2);
            pv[3] = tg | (unsigned)__builtin_bit_cast(unsigned short, (_Float16)r3);
            st_u4_dev(wslot + (size_t)((t + 2) & 1) * RING_WORDS, pv);
        }
        if (CANARY) {
            // drain own stores; barrier = whole WG's ring words committed at L3;
            // then one canary store announces tag t+2 for this WG.
            drain_vm();
            __syncthreads();
            if (tid == 0) st_dw_dev(&canary[(g << 4) + m], (unsigned)(t + 2));
        }
    }
}

// ================= SLOW kernel: R4-proven sc0sc1 + flags (4KB ws footprint) =============
__global__ void __launch_bounds__(256, 1)
rnn_slow(const float* __restrict__ inp, const float* __restrict__ nz,
         const float* __restrict__ W, const float* __restrict__ bias,
         const void* __restrict__ mask, unsigned* flags, float* out) {
    const int bid  = blockIdx.x;
    const int g    = bid & 15;
    const int m    = bid >> 4;
    const int tid  = threadIdx.x;
    const int w    = tid >> 6;
    const int lane = tid & 63;
    const int l15  = lane & 15;
    const int lq   = lane >> 4;

    __shared__ __align__(16) float part[2][4][16][68];

    bool mask_f32, mask_u8;
    detect_mask(mask, lane, mask_f32, mask_u8);
    f16x8 bfr[4][8];
    build_bfr(W, mask, mask_f32, mask_u8, m, w, l15, lq, bfr);

    const int orow = tid >> 4;
    const int ocol = (tid & 15) << 2;
    const int grow = 16 * g + orow;
    const int gcol = 64 * m + ocol;
    const float4 b4 = *(const float4*)(bias + gcol);

    float x0 = 0.f, x1 = 0.f, x2 = 0.f, x3 = 0.f;

    unsigned* const myflag  = &flags[(g << 6) + (m << 2) + w];
    unsigned* const myflags = flags + (g << 6) + (w << 4);

    {
        f32x4 z = {0.f, 0.f, 0.f, 0.f};
        st_f4_dev(out + (size_t)grow * NNEUR + gcol, z);
    }
    drain_vm();
    __builtin_amdgcn_sched_barrier(0);
    if (lane == 0) st_dw_dev(myflag, 1u);

    for (int t = 0; t < T_STEPS; ++t) {
        const size_t io = (size_t)t * BN + (size_t)grow * NNEUR + gcol;
        const float4 in4 = *(const float4*)(inp + io);
        const float4 nz4 = *(const float4*)(nz + io);

        {
            const unsigned tgt = (unsigned)(t + 1);
            if (lane < 16) {
                const unsigned* fp = &myflags[lane];
                int spin = 0;
                unsigned v;
                do {
                    v = ld_dw_dev(fp);
                    if (v >= tgt) break;
                    __builtin_amdgcn_s_sleep(1);
                } while (++spin < (1 << 14));
            }
            __builtin_amdgcn_sched_barrier(0);
        }

        f32x4 alo[8], ahi[8];
        {
            const float* ab = out + (size_t)t * BN + (size_t)(16 * g + l15) * NNEUR
                              + 256 * w + 8 * lq;
            #pragma unroll
            for (int kk = 0; kk < 8; ++kk) {
                alo[kk] = ld_f4_dev(ab + 32 * kk);
                ahi[kk] = ld_f4_dev(ab + 32 * kk + 4);
            }
        }
        drain_vm();
        __builtin_amdgcn_sched_barrier(0);

        f16x8 a[8];
        #pragma unroll
        for (int kk = 0; kk < 8; ++kk) {
            f16x8 av;
            av[0] = (_Float16)alo[kk][0]; av[1] = (_Float16)alo[kk][1];
            av[2] = (_Float16)alo[kk][2]; av[3] = (_Float16)alo[kk][3];
            av[4] = (_Float16)ahi[kk][0]; av[5] = (_Float16)ahi[kk][1];
            av[6] = (_Float16)ahi[kk][2]; av[7] = (_Float16)ahi[kk][3];
            a[kk] = av;
        }

        f32x4 acc[4] = {};
        #pragma unroll
        for (int kk = 0; kk < 8; ++kk)
            #pragma unroll
            for (int ns = 0; ns < 4; ++ns)
                acc[ns] = __builtin_amdgcn_mfma_f32_16x16x32_f16(a[kk], bfr[ns][kk], acc[ns], 0, 0, 0);

        const int pb = t & 1;
        #pragma unroll
        for (int ns = 0; ns < 4; ++ns)
            #pragma unroll
            for (int r = 0; r < 4; ++r)
                part[pb][w][(lq << 2) + r][(ns << 4) + l15] = acc[ns][r];

        __syncthreads();

        f32x4 s = *(const f32x4*)&part[pb][0][orow][ocol];
        #pragma unroll
        for (int wv = 1; wv < 4; ++wv)
            s += *(const f32x4*)&part[pb][wv][orow][ocol];

        x0 = 0.9f * x0 + 0.1f * (s[0] + in4.x + b4.x) + 0.003f * nz4.x;
        x1 = 0.9f * x1 + 0.1f * (s[1] + in4.y + b4.y) + 0.003f * nz4.y;
        x2 = 0.9f * x2 + 0.1f * (s[2] + in4.z + b4.z) + 0.003f * nz4.z;
        x3 = 0.9f * x3 + 0.1f * (s[3] + in4.w + b4.w) + 0.003f * nz4.w;

        {
            f32x4 rv = {tanhf(x0), tanhf(x1), tanhf(x2), tanhf(x3)};
            st_f4_dev(out + (size_t)(t + 1) * BN + (size_t)grow * NNEUR + gcol, rv);
        }
        drain_vm();
        __builtin_amdgcn_sched_barrier(0);
        if (lane == 0) st_dw_dev(myflag, (unsigned)(t + 2));
    }
}

extern "C" void kernel_launch(void* const* d_in, const int* in_sizes, int n_in,
                              void* d_out, int out_size, void* d_ws, size_t ws_size,
                              hipStream_t stream) {
    const float* inp  = (const float*)d_in[0];
    const float* nz   = (const float*)d_in[1];
    const float* W    = (const float*)d_in[2];
    const float* bias = (const float*)d_in[3];
    const void*  mask = d_in[4];
    float* out = (float*)d_out;

    const size_t ring_bytes = (size_t)2 * RING_WORDS * sizeof(unsigned);  // 2 MiB
    unsigned* ws = (unsigned*)d_ws;
    void* args[] = {(void*)&inp, (void*)&nz, (void*)&W, (void*)&bias,
                    (void*)&mask, (void*)&ws, (void*)&out};

    if (ws_size >= ring_bytes + 4096) {
        // canary-gated fetch: canary block [0,4KB), ring [4KB, 4KB+2MiB)
        (void)hipMemsetAsync(ws, 0, ring_bytes + 4096, stream);
        hipError_t e = hipLaunchCooperativeKernel((const void*)rnn_fast<true>,
                                                  dim3(256), dim3(256), args, 0, stream);
        if (e != hipSuccess)
            rnn_fast<true><<<dim3(256), dim3(256), 0, stream>>>(inp, nz, W, bias, mask, ws, out);
    } else if (ws_size >= ring_bytes) {
        // R7-proven full-poll tagged ring
        (void)hipMemsetAsync(ws, 0, ring_bytes, stream);
        hipError_t e = hipLaunchCooperativeKernel((const void*)rnn_fast<false>,
                                                  dim3(256), dim3(256), args, 0, stream);
        if (e != hipSuccess)
            rnn_fast<false><<<dim3(256), dim3(256), 0, stream>>>(inp, nz, W, bias, mask, ws, out);
    } else {
        // R4-proven slow path: flags only, 4 KiB
        (void)hipMemsetAsync(ws, 0, 4096, stream);
        hipError_t e = hipLaunchCooperativeKernel((const void*)rnn_slow,
                                                  dim3(256), dim3(256), args, 0, stream);
        if (e != hipSuccess)
            rnn_slow<<<dim3(256), dim3(256), 0, stream>>>(inp, nz, W, bias, mask, ws, out);
    }
}

// Round 12
// 1436.570 us; speedup vs baseline: 1.2708x; 1.2708x over previous
//
#include <hip/hip_runtime.h>
#include <cmath>

#define T_STEPS 300
#define NBATCH  256
#define NNEUR   1024
#define BN      (NBATCH * NNEUR)
#define RING_WORDS (NBATCH * NNEUR)   // one ring slot = 256x1024 u32 = 1 MiB

typedef _Float16 f16x8 __attribute__((ext_vector_type(8)));
typedef float    f32x4 __attribute__((ext_vector_type(4)));
typedef unsigned u32x4 __attribute__((ext_vector_type(4)));

// ---- device-scope primitives (commit at / read from the L3 coherence point) -----------
__device__ __forceinline__ void st_u4_dev(unsigned* p, u32x4 v) {
    asm volatile("global_store_dwordx4 %0, %1, off sc0 sc1" :: "v"(p), "v"(v) : "memory");
}
__device__ __forceinline__ u32x4 ld_u4_dev(const unsigned* p) {
    u32x4 d; asm volatile("global_load_dwordx4 %0, %1, off sc0 sc1" : "=v"(d) : "v"(p)); return d;
}
__device__ __forceinline__ void st_f4_dev(float* p, f32x4 v) {
    asm volatile("global_store_dwordx4 %0, %1, off sc0 sc1" :: "v"(p), "v"(v) : "memory");
}
__device__ __forceinline__ f32x4 ld_f4_dev(const float* p) {
    f32x4 d; asm volatile("global_load_dwordx4 %0, %1, off sc0 sc1" : "=v"(d) : "v"(p)); return d;
}
__device__ __forceinline__ void st_dw_dev(unsigned* p, unsigned v) {
    asm volatile("global_store_dword %0, %1, off sc0 sc1" :: "v"(p), "v"(v) : "memory");
}
__device__ __forceinline__ unsigned ld_dw_dev(const unsigned* p) {
    unsigned v;
    asm volatile("global_load_dword %0, %1, off sc0 sc1\n\ts_waitcnt vmcnt(0)"
                 : "=v"(v) : "v"(p) : "memory");
    return v;
}
__device__ __forceinline__ void drain_vm() {
    asm volatile("s_waitcnt vmcnt(0)" ::: "memory");
}
// branchless tanh: 1 - 2/(e^{2x}+1); ~1e-6 abs error (margin: threshold/absmax = 4.8x)
__device__ __forceinline__ float fast_tanh(float x) {
    float e = __expf(2.0f * x);
    return 1.0f - 2.0f / (e + 1.0f);
}

// ---- shared prologue helpers -----------------------------------------------------------
__device__ __forceinline__ void detect_mask(const void* mask, int lane,
                                            bool& mask_f32, bool& mask_u8) {
    unsigned mb = 0;
    const unsigned* m32 = (const unsigned*)mask;
    for (int idx = lane; idx < 1024; idx += 64) {
        unsigned v = m32[idx];
        if (v == 0x3F800000u) mb |= 2u;
        else if (v > 1u)      mb |= 1u;
    }
    mask_f32 = __ballot(mb & 2u) != 0ull;
    mask_u8  = !mask_f32 && (__ballot(mb & 1u) != 0ull);
}

__device__ __forceinline__ void build_bfr(const float* W, const void* mask,
                                          bool mask_f32, bool mask_u8,
                                          int m, int w, int l15, int lq, f16x8 bfr[4][8]) {
    #pragma unroll
    for (int ns = 0; ns < 4; ++ns) {
        const size_t rowbase = (size_t)(64 * m + 16 * ns + l15) * NNEUR + 256 * w + 8 * lq;
        #pragma unroll
        for (int kk = 0; kk < 8; ++kk) {
            const size_t i0 = rowbase + 32 * kk;
            f16x8 bv;
            #pragma unroll
            for (int j = 0; j < 8; ++j) {
                const size_t i = i0 + j;
                bool mv;
                if (mask_f32)     mv = ((const float*)mask)[i] != 0.0f;
                else if (mask_u8) mv = ((const unsigned char*)mask)[i] != 0;
                else              mv = ((const int*)mask)[i] != 0;
                bv[j] = (_Float16)(mv ? W[i] : 0.0f);
            }
            bfr[ns][kk] = bv;
        }
    }
}

// ================= FAST kernel: tagged ring + subset-probe poll =========================
// word = ((t+1)<<16)|f16bits(r_t); slot = (t+1)&1; ring-reuse skew<=1 proof as R6/R7.
// Poll: spin (WITH s_sleep backoff, as R7's proven loop) on 4 probe dwordx4
// (wv[0],[4],[8],[12] = kk 0,2,4,6) -> 64B/lane/iter, 4x less traffic than full-poll,
// yet covers all 4 producer members and all 16 producer waves. Then fetch the remaining
// 12 vectors ONCE and tag-validate (self-validating words = correctness regardless).
__global__ void __launch_bounds__(256, 1)
rnn_fast(const float* __restrict__ inp, const float* __restrict__ nz,
         const float* __restrict__ W, const float* __restrict__ bias,
         const void* __restrict__ mask, unsigned* ring, float* out) {
    const int bid  = blockIdx.x;
    const int g    = bid & 15;
    const int m    = bid >> 4;
    const int tid  = threadIdx.x;
    const int w    = tid >> 6;
    const int lane = tid & 63;
    const int l15  = lane & 15;
    const int lq   = lane >> 4;

    __shared__ __align__(16) float part[2][4][16][68];

    bool mask_f32, mask_u8;
    detect_mask(mask, lane, mask_f32, mask_u8);
    f16x8 bfr[4][8];
    build_bfr(W, mask, mask_f32, mask_u8, m, w, l15, lq, bfr);

    const int orow = tid >> 4;
    const int ocol = (tid & 15) << 2;
    const int grow = 16 * g + orow;
    const int gcol = 64 * m + ocol;
    const float4 b4 = *(const float4*)(bias + gcol);

    float x0 = 0.f, x1 = 0.f, x2 = 0.f, x3 = 0.f;

    // r_0 = tanh(0) = 0: out slice only; t=0 iteration skips the poll entirely.
    *(float4*)(out + (size_t)grow * NNEUR + gcol) = make_float4(0.f, 0.f, 0.f, 0.f);

    const unsigned* rbase = ring + (size_t)(16 * g + l15) * NNEUR + 256 * w + 8 * lq;
    unsigned* const wslot = ring + (size_t)grow * NNEUR + gcol;

    for (int t = 0; t < T_STEPS; ++t) {
        const size_t io = (size_t)t * BN + (size_t)grow * NNEUR + gcol;
        const float4 in4 = *(const float4*)(inp + io);
        const float4 nz4 = *(const float4*)(nz + io);

        f16x8 a[8];
        if (t > 0) {
            const unsigned tgu = (unsigned)(t + 1);
            const unsigned tgt = tgu << 16;
            const unsigned* rb = rbase + (size_t)(tgu & 1) * RING_WORDS;
            u32x4 wv[16];

            {   // ---- probe spin: 4 dwordx4 + backoff; covers all producer waves ----
                int budget = 1 << 14;
                for (;;) {
                    wv[0]  = ld_u4_dev(rb);
                    wv[4]  = ld_u4_dev(rb + 64);
                    wv[8]  = ld_u4_dev(rb + 128);
                    wv[12] = ld_u4_dev(rb + 192);
                    drain_vm();
                    unsigned bad = 0;
                    #pragma unroll
                    for (int i = 0; i < 16; i += 4) {
                        const u32x4 x = wv[i] ^ tgt;      // hi16 == 0 iff fresh
                        bad |= (x[0] | x[1] | x[2] | x[3]) & 0xFFFF0000u;
                    }
                    if (__ballot(bad != 0u) == 0ull) break;
                    if (--budget <= 0) break;             // failsafe: never hang
                    __builtin_amdgcn_s_sleep(1);          // backoff (R7-proven; no fabric hammer)
                }
            }
            {   // ---- fetch remaining 12 vectors once + validate (expected 1 iter) ----
                int budget = 1 << 10;
                for (;;) {
                    wv[1]  = ld_u4_dev(rb + 4);   wv[2]  = ld_u4_dev(rb + 32);
                    wv[3]  = ld_u4_dev(rb + 36);  wv[5]  = ld_u4_dev(rb + 68);
                    wv[6]  = ld_u4_dev(rb + 96);  wv[7]  = ld_u4_dev(rb + 100);
                    wv[9]  = ld_u4_dev(rb + 132); wv[10] = ld_u4_dev(rb + 160);
                    wv[11] = ld_u4_dev(rb + 164); wv[13] = ld_u4_dev(rb + 196);
                    wv[14] = ld_u4_dev(rb + 224); wv[15] = ld_u4_dev(rb + 228);
                    drain_vm();
                    unsigned bad = 0;
                    #pragma unroll
                    for (int i = 0; i < 16; ++i) {
                        if ((i & 3) == 0) continue;       // probe words already validated
                        const u32x4 x = wv[i] ^ tgt;
                        bad |= (x[0] | x[1] | x[2] | x[3]) & 0xFFFF0000u;
                    }
                    if (__ballot(bad != 0u) == 0ull) break;
                    if (--budget <= 0) break;             // failsafe: never hang
                    __builtin_amdgcn_s_sleep(1);
                }
            }
            #pragma unroll
            for (int kk = 0; kk < 8; ++kk) {
                const u32x4 lo = wv[2 * kk], hi = wv[2 * kk + 1];
                u32x4 p;
                p[0] = (lo[0] & 0xFFFFu) | (lo[1] << 16);
                p[1] = (lo[2] & 0xFFFFu) | (lo[3] << 16);
                p[2] = (hi[0] & 0xFFFFu) | (hi[1] << 16);
                p[3] = (hi[2] & 0xFFFFu) | (hi[3] << 16);
                a[kk] = __builtin_bit_cast(f16x8, p);
            }
        } else {
            #pragma unroll
            for (int kk = 0; kk < 8; ++kk) a[kk] = f16x8{};
        }

        f32x4 acc[4] = {};
        #pragma unroll
        for (int kk = 0; kk < 8; ++kk)
            #pragma unroll
            for (int ns = 0; ns < 4; ++ns)
                acc[ns] = __builtin_amdgcn_mfma_f32_16x16x32_f16(a[kk], bfr[ns][kk], acc[ns], 0, 0, 0);

        const int pb = t & 1;
        #pragma unroll
        for (int ns = 0; ns < 4; ++ns)
            #pragma unroll
            for (int r = 0; r < 4; ++r)
                part[pb][w][(lq << 2) + r][(ns << 4) + l15] = acc[ns][r];

        __syncthreads();

        f32x4 s = *(const f32x4*)&part[pb][0][orow][ocol];
        #pragma unroll
        for (int wv2 = 1; wv2 < 4; ++wv2)
            s += *(const f32x4*)&part[pb][wv2][orow][ocol];

        x0 = 0.9f * x0 + 0.1f * (s[0] + in4.x + b4.x) + 0.003f * nz4.x;
        x1 = 0.9f * x1 + 0.1f * (s[1] + in4.y + b4.y) + 0.003f * nz4.y;
        x2 = 0.9f * x2 + 0.1f * (s[2] + in4.z + b4.z) + 0.003f * nz4.z;
        x3 = 0.9f * x3 + 0.1f * (s[3] + in4.w + b4.w) + 0.003f * nz4.w;

        const float r0 = fast_tanh(x0), r1 = fast_tanh(x1),
                    r2 = fast_tanh(x2), r3 = fast_tanh(x3);

        *(float4*)(out + (size_t)(t + 1) * BN + (size_t)grow * NNEUR + gcol)
            = make_float4(r0, r1, r2, r3);

        {   // fire-and-forget tagged publish (no drain, no flag, no barrier)
            const unsigned tg = (unsigned)(t + 2) << 16;
            u32x4 pv;
            pv[0] = tg | (unsigned)__builtin_bit_cast(unsigned short, (_Float16)r0);
            pv[1] = tg | (unsigned)__builtin_bit_cast(unsigned short, (_Float16)r1);
            pv[2] = tg | (unsigned)__builtin_bit_cast(unsigned short, (_Float16)r2);
            pv[3] = tg | (unsigned)__builtin_bit_cast(unsigned short, (_Float16)r3);
            st_u4_dev(wslot + (size_t)((t + 2) & 1) * RING_WORDS, pv);
        }
    }
}

// ================= SLOW kernel: R4-proven sc0sc1 + flags (4KB ws footprint) =============
__global__ void __launch_bounds__(256, 1)
rnn_slow(const float* __restrict__ inp, const float* __restrict__ nz,
         const float* __restrict__ W, const float* __restrict__ bias,
         const void* __restrict__ mask, unsigned* flags, float* out) {
    const int bid  = blockIdx.x;
    const int g    = bid & 15;
    const int m    = bid >> 4;
    const int tid  = threadIdx.x;
    const int w    = tid >> 6;
    const int lane = tid & 63;
    const int l15  = lane & 15;
    const int lq   = lane >> 4;

    __shared__ __align__(16) float part[2][4][16][68];

    bool mask_f32, mask_u8;
    detect_mask(mask, lane, mask_f32, mask_u8);
    f16x8 bfr[4][8];
    build_bfr(W, mask, mask_f32, mask_u8, m, w, l15, lq, bfr);

    const int orow = tid >> 4;
    const int ocol = (tid & 15) << 2;
    const int grow = 16 * g + orow;
    const int gcol = 64 * m + ocol;
    const float4 b4 = *(const float4*)(bias + gcol);

    float x0 = 0.f, x1 = 0.f, x2 = 0.f, x3 = 0.f;

    unsigned* const myflag  = &flags[(g << 6) + (m << 2) + w];
    unsigned* const myflags = flags + (g << 6) + (w << 4);

    {
        f32x4 z = {0.f, 0.f, 0.f, 0.f};
        st_f4_dev(out + (size_t)grow * NNEUR + gcol, z);
    }
    drain_vm();
    __builtin_amdgcn_sched_barrier(0);
    if (lane == 0) st_dw_dev(myflag, 1u);

    for (int t = 0; t < T_STEPS; ++t) {
        const size_t io = (size_t)t * BN + (size_t)grow * NNEUR + gcol;
        const float4 in4 = *(const float4*)(inp + io);
        const float4 nz4 = *(const float4*)(nz + io);

        {
            const unsigned tgt = (unsigned)(t + 1);
            if (lane < 16) {
                const unsigned* fp = &myflags[lane];
                int spin = 0;
                unsigned v;
                do {
                    v = ld_dw_dev(fp);
                    if (v >= tgt) break;
                    __builtin_amdgcn_s_sleep(1);
                } while (++spin < (1 << 14));
            }
            __builtin_amdgcn_sched_barrier(0);
        }

        f32x4 alo[8], ahi[8];
        {
            const float* ab = out + (size_t)t * BN + (size_t)(16 * g + l15) * NNEUR
                              + 256 * w + 8 * lq;
            #pragma unroll
            for (int kk = 0; kk < 8; ++kk) {
                alo[kk] = ld_f4_dev(ab + 32 * kk);
                ahi[kk] = ld_f4_dev(ab + 32 * kk + 4);
            }
        }
        drain_vm();
        __builtin_amdgcn_sched_barrier(0);

        f16x8 a[8];
        #pragma unroll
        for (int kk = 0; kk < 8; ++kk) {
            f16x8 av;
            av[0] = (_Float16)alo[kk][0]; av[1] = (_Float16)alo[kk][1];
            av[2] = (_Float16)alo[kk][2]; av[3] = (_Float16)alo[kk][3];
            av[4] = (_Float16)ahi[kk][0]; av[5] = (_Float16)ahi[kk][1];
            av[6] = (_Float16)ahi[kk][2]; av[7] = (_Float16)ahi[kk][3];
            a[kk] = av;
        }

        f32x4 acc[4] = {};
        #pragma unroll
        for (int kk = 0; kk < 8; ++kk)
            #pragma unroll
            for (int ns = 0; ns < 4; ++ns)
                acc[ns] = __builtin_amdgcn_mfma_f32_16x16x32_f16(a[kk], bfr[ns][kk], acc[ns], 0, 0, 0);

        const int pb = t & 1;
        #pragma unroll
        for (int ns = 0; ns < 4; ++ns)
            #pragma unroll
            for (int r = 0; r < 4; ++r)
                part[pb][w][(lq << 2) + r][(ns << 4) + l15] = acc[ns][r];

        __syncthreads();

        f32x4 s = *(const f32x4*)&part[pb][0][orow][ocol];
        #pragma unroll
        for (int wv = 1; wv < 4; ++wv)
            s += *(const f32x4*)&part[pb][wv][orow][ocol];

        x0 = 0.9f * x0 + 0.1f * (s[0] + in4.x + b4.x) + 0.003f * nz4.x;
        x1 = 0.9f * x1 + 0.1f * (s[1] + in4.y + b4.y) + 0.003f * nz4.y;
        x2 = 0.9f * x2 + 0.1f * (s[2] + in4.z + b4.z) + 0.003f * nz4.z;
        x3 = 0.9f * x3 + 0.1f * (s[3] + in4.w + b4.w) + 0.003f * nz4.w;

        {
            f32x4 rv = {tanhf(x0), tanhf(x1), tanhf(x2), tanhf(x3)};
            st_f4_dev(out + (size_t)(t + 1) * BN + (size_t)grow * NNEUR + gcol, rv);
        }
        drain_vm();
        __builtin_amdgcn_sched_barrier(0);
        if (lane == 0) st_dw_dev(myflag, (unsigned)(t + 2));
    }
}

extern "C" void kernel_launch(void* const* d_in, const int* in_sizes, int n_in,
                              void* d_out, int out_size, void* d_ws, size_t ws_size,
                              hipStream_t stream) {
    const float* inp  = (const float*)d_in[0];
    const float* nz   = (const float*)d_in[1];
    const float* W    = (const float*)d_in[2];
    const float* bias = (const float*)d_in[3];
    const void*  mask = d_in[4];
    float* out = (float*)d_out;

    const size_t ring_bytes = (size_t)2 * RING_WORDS * sizeof(unsigned);  // 2 MiB
    unsigned* ws = (unsigned*)d_ws;
    void* args[] = {(void*)&inp, (void*)&nz, (void*)&W, (void*)&bias,
                    (void*)&mask, (void*)&ws, (void*)&out};

    if (ws_size >= ring_bytes) {
        // tagged ring + subset-probe poll. Zero every call (exact-match tags repeat).
        (void)hipMemsetAsync(ws, 0, ring_bytes, stream);
        hipError_t e = hipLaunchCooperativeKernel((const void*)rnn_fast,
                                                  dim3(256), dim3(256), args, 0, stream);
        if (e != hipSuccess)
            rnn_fast<<<dim3(256), dim3(256), 0, stream>>>(inp, nz, W, bias, mask, ws, out);
    } else {
        // R4-proven slow path: flags only, 4 KiB
        (void)hipMemsetAsync(ws, 0, 4096, stream);
        hipError_t e = hipLaunchCooperativeKernel((const void*)rnn_slow,
                                                  dim3(256), dim3(256), args, 0, stream);
        if (e != hipSuccess)
            rnn_slow<<<dim3(256), dim3(256), 0, stream>>>(inp, nz, W, bias, mask, ws, out);
    }
}